// Round 1
// baseline (690.507 us; speedup 1.0000x reference)
//
#include <hip/hip_runtime.h>

typedef _Float16 f16;
typedef f16 f16x4 __attribute__((ext_vector_type(4)));
typedef f16 f16x8 __attribute__((ext_vector_type(8)));
typedef float f32x4 __attribute__((ext_vector_type(4)));

#define BB 32
#define NN 1024
#define HH 128
#define ROWS (BB*NN)          // 32768
#define EPS 1e-5f

__device__ __forceinline__ f16 f2h(float x) { return (f16)x; }

typedef __attribute__((address_space(1))) const void gv_t;
typedef __attribute__((address_space(3))) void lv_t;
__device__ __forceinline__ void gl_lds16(const void* g, void* l) {
  __builtin_amdgcn_global_load_lds((gv_t*)g, (lv_t*)l, 16, 0, 0);
}

// ---------------------------------------------------------------------------
// prep0: pack/convert kernel (79 blocks x 256)
//  blk0: Wh f16[128][128] from W_msg (stride 131)
//  blk1: Wupd f16[128][256]
//  blk2: We f32[128][3], zero sums[256]
//  blk3..6: zero e_agg
//  blk7..14: mask slabs (tj): maskf16[j][i], maskT_f16[i][j], deg[j] exact
//  blk15..78: node f32 -> f16 (nodeh)
// ---------------------------------------------------------------------------
__global__ __launch_bounds__(256) void prep0_k(
    const float* __restrict__ W_msg, const float* __restrict__ W_upd,
    const float* __restrict__ node, const int* __restrict__ adj,
    f16* __restrict__ Wh, f16* __restrict__ Wupd, float* __restrict__ We,
    float* __restrict__ e_agg, float* __restrict__ deg, float* __restrict__ sums,
    f16* __restrict__ nodeh, f16* __restrict__ maskf, f16* __restrict__ maskT)
{
  const int blk = blockIdx.x, t = threadIdx.x;
  if (blk == 0) {
    for (int idx = t; idx < HH*HH; idx += 256) {
      const int o = idx >> 7, h = idx & 127;
      Wh[idx] = f2h(W_msg[o*131 + h]);
    }
  } else if (blk == 1) {
    for (int idx = t; idx < HH*256; idx += 256)
      Wupd[idx] = f2h(W_upd[idx]);
  } else if (blk == 2) {
    for (int idx = t; idx < HH*3; idx += 256)
      We[idx] = W_msg[(idx/3)*131 + 128 + (idx % 3)];
    if (t < 256) sums[t] = 0.f;
  } else if (blk < 7) {
    const int base = (blk - 3) * 24576 + t;
    #pragma unroll
    for (int r = 0; r < 96; r++) e_agg[base + r*256] = 0.f;
  } else if (blk < 15) {
    // mask slab: rows j in [tj*128, tj*128+128), all i; transpose via LDS
    __shared__ f16 ldsT[128][136];     // [i_local][j_local], padded
    __shared__ float degl[128];
    const int tj = blk - 7;
    if (t < 128) degl[t] = 0.f;
    __syncthreads();
    for (int ti = 0; ti < 8; ti++) {
      #pragma unroll
      for (int pass = 0; pass < 16; pass++) {
        const int q = pass*256 + t;
        const int row = q >> 5, c4 = (q & 31) << 2;    // row 0..127, col step 4
        const int4 m = *(const int4*)&adj[(long)(tj*128 + row)*NN + ti*128 + c4];
        f16x4 hv;
        hv[0] = (m.x > 0) ? (f16)1.0f : (f16)0.0f;
        hv[1] = (m.y > 0) ? (f16)1.0f : (f16)0.0f;
        hv[2] = (m.z > 0) ? (f16)1.0f : (f16)0.0f;
        hv[3] = (m.w > 0) ? (f16)1.0f : (f16)0.0f;
        *(f16x4*)&maskf[(long)(tj*128 + row)*NN + ti*128 + c4] = hv;
        ldsT[c4 + 0][row] = hv[0];
        ldsT[c4 + 1][row] = hv[1];
        ldsT[c4 + 2][row] = hv[2];
        ldsT[c4 + 3][row] = hv[3];
        const int cnt = (m.x > 0) + (m.y > 0) + (m.z > 0) + (m.w > 0);
        if (cnt) atomicAdd(&degl[row], (float)cnt);
      }
      __syncthreads();
      #pragma unroll
      for (int pass = 0; pass < 8; pass++) {
        const int q = pass*256 + t;
        const int rT = q >> 4, c8 = (q & 15) << 3;
        *(uint4*)&maskT[(long)(ti*128 + rT)*NN + tj*128 + c8] =
            *(const uint4*)&ldsT[rT][c8];
      }
      __syncthreads();
    }
    if (t < 128) deg[tj*128 + t] = degl[t];
  } else {
    // node -> f16, flat float4 space
    const long base = (long)(blk - 15)*256 + t;
    #pragma unroll
    for (int p = 0; p < 64; p++) {
      const long idx = base + (long)p*16384;
      const float4 v = ((const float4*)node)[idx];
      f16x4 hv; hv[0] = f2h(v.x); hv[1] = f2h(v.y); hv[2] = f2h(v.z); hv[3] = f2h(v.w);
      *(f16x4*)&nodeh[idx << 2] = hv;
    }
  }
}

// ---------------------------------------------------------------------------
// Phase B megakernel: 1280 blocks x 256.
//  blk [0,256): gemm0 — h_part_T[b][o][i] = sum_h Wh[o][h]*nodeh[b,i,h]
//  blk [256,1280): eagg — e_agg[b][j][c] += sum_i E[b,i,j,c]*maskT[i][j]
// ---------------------------------------------------------------------------
__global__ __launch_bounds__(256) void phaseB_k(
    const f16* __restrict__ nodeh, const float* __restrict__ E,
    const f16* __restrict__ maskT, const f16* __restrict__ Wh,
    f16* __restrict__ h_part_T, float* __restrict__ e_agg)
{
  __shared__ f16 As[128*32];
  __shared__ f16 Bs[128*32];
  const int tid = threadIdx.x;

  if (blockIdx.x >= 256) {
    // ---- eagg path: coalesced mask reads (maskT[i][j], 128B/wave) ----
    const int e  = blockIdx.x - 256;        // 0..1023
    const int bb = e >> 5;
    const int r5 = e & 31;
    const int jt = r5 & 3;                  // 4 j-tiles of 256
    const int ih = r5 >> 2;                 // 8 i-chunks of 128
    const int j  = (jt << 8) + tid;
    const int i0 = ih << 7;
    const float* Ep = E + (long)bb*3145728 + (long)i0*3072 + (long)j*3;
    const f16*   Mp = maskT + (long)i0*NN + j;
    float a0 = 0.f, a1 = 0.f, a2 = 0.f;
    for (int ii = 0; ii < 128; ii += 8) {
      float m[8];
      #pragma unroll
      for (int v = 0; v < 8; v++) m[v] = (float)Mp[(long)(ii + v)*NN];
      float ev[8][3];
      #pragma unroll
      for (int v = 0; v < 8; v++) {
        const float* q = Ep + (long)(ii + v)*3072;
        ev[v][0] = q[0]; ev[v][1] = q[1]; ev[v][2] = q[2];
      }
      #pragma unroll
      for (int v = 0; v < 8; v++) {
        a0 = fmaf(m[v], ev[v][0], a0);
        a1 = fmaf(m[v], ev[v][1], a1);
        a2 = fmaf(m[v], ev[v][2], a2);
      }
    }
    const long eb = ((long)bb*NN + j)*3;
    atomicAdd(&e_agg[eb],     a0);
    atomicAdd(&e_agg[eb + 1], a1);
    atomicAdd(&e_agg[eb + 2], a2);
    return;
  }

  // ---- gemm0 path: M=128 (o), N=128 tile (i), K=128, gl_lds staging ----
  const int g  = blockIdx.x;
  const int nt = g & 7, bb = g >> 3;
  const int nbase = nt << 7;
  const int lane = tid & 63, wave = tid >> 6;
  const int wm = (wave & 1) << 6, wn = (wave >> 1) << 6;

  f32x4 acc[2][4], acc2[2][4];
  #pragma unroll
  for (int i = 0; i < 2; i++)
    #pragma unroll
    for (int j = 0; j < 4; j++)
      #pragma unroll
      for (int r = 0; r < 4; r++) { acc[i][j][r] = 0.f; acc2[i][j][r] = 0.f; }

  for (int k0 = 0; k0 < HH; k0 += 32) {
    #pragma unroll
    for (int p = 0; p < 2; p++) {
      const int q = (p << 8) + tid;
      const int row = q >> 2, kp = (q & 3) << 3;
      gl_lds16(&Wh[(long)row*HH + k0 + kp], &As[q << 3]);
      gl_lds16(&nodeh[(long)((bb << 10) + nbase + row)*HH + k0 + kp], &Bs[q << 3]);
    }
    __syncthreads();
    f16x8 af[4], bf[4];
    #pragma unroll
    for (int i = 0; i < 4; i++) {
      af[i] = *(const f16x8*)&As[((wm + (i << 4) + (lane & 15)) << 5) + ((lane >> 4) << 3)];
      bf[i] = *(const f16x8*)&Bs[((wn + (i << 4) + (lane & 15)) << 5) + ((lane >> 4) << 3)];
    }
    #pragma unroll
    for (int i = 0; i < 2; i++)
      #pragma unroll
      for (int j = 0; j < 4; j++) {
        acc[i][j]  = __builtin_amdgcn_mfma_f32_16x16x32_f16(af[i],     bf[j], acc[i][j],  0, 0, 0);
        acc2[i][j] = __builtin_amdgcn_mfma_f32_16x16x32_f16(af[i + 2], bf[j], acc2[i][j], 0, 0, 0);
      }
    __syncthreads();
  }

  f16* out = h_part_T + (long)bb * (HH*NN);
  const int rb = (lane >> 4) << 2, cb = lane & 15;
  #pragma unroll
  for (int i = 0; i < 4; i++)
    #pragma unroll
    for (int r = 0; r < 4; r++) {
      const int gm = wm + (i << 4) + rb + r;                    // o
      #pragma unroll
      for (int j = 0; j < 4; j++) {
        const int gn = nbase + wn + (j << 4) + cb;              // i
        const float v = (i < 2) ? acc[i][j][r] : acc2[i - 2][j][r];
        out[(long)gm*NN + gn] = f2h(v);
      }
    }
}

// ---------------------------------------------------------------------------
// gemm1: messages[b,j,o] = sum_i maskf[j,i]*h_part_T[b][o][i] + deg[j]*b_msg[o]
//        + e_agg[b,j,:]·We[o,:]  — pure f16 copies via global_load_lds
// ---------------------------------------------------------------------------
__global__ __launch_bounds__(256) void gemm1_k(
    const f16* __restrict__ maskf, const f16* __restrict__ hp,
    const float* __restrict__ deg, const float* __restrict__ b_msg,
    const float* __restrict__ e_agg, const float* __restrict__ We,
    f16* __restrict__ msgs)
{
  const int mt = blockIdx.x, bb = blockIdx.z;
  const int jb = mt << 7;
  __shared__ f16 As[128*32];
  __shared__ f16 Bs[128*32];
  const int tid = threadIdx.x, lane = tid & 63, wave = tid >> 6;
  const int wm = (wave & 1) << 6, wn = (wave >> 1) << 6;

  f32x4 acc[4][4];
  #pragma unroll
  for (int i = 0; i < 4; i++)
    #pragma unroll
    for (int j = 0; j < 4; j++)
      #pragma unroll
      for (int r = 0; r < 4; r++) acc[i][j][r] = 0.f;

  for (int k0 = 0; k0 < NN; k0 += 32) {
    #pragma unroll
    for (int p = 0; p < 2; p++) {
      const int q = (p << 8) + tid;
      const int row = q >> 2, kp = (q & 3) << 3;
      gl_lds16(&maskf[(long)(jb + row)*NN + k0 + kp], &As[q << 3]);
      gl_lds16(&hp[(long)bb*(HH*NN) + (long)row*NN + k0 + kp], &Bs[q << 3]);
    }
    __syncthreads();
    f16x8 af[4], bf[4];
    #pragma unroll
    for (int i = 0; i < 4; i++) {
      af[i] = *(const f16x8*)&As[((wm + (i << 4) + (lane & 15)) << 5) + ((lane >> 4) << 3)];
      bf[i] = *(const f16x8*)&Bs[((wn + (i << 4) + (lane & 15)) << 5) + ((lane >> 4) << 3)];
    }
    #pragma unroll
    for (int i = 0; i < 4; i++)
      #pragma unroll
      for (int j = 0; j < 4; j++)
        acc[i][j] = __builtin_amdgcn_mfma_f32_16x16x32_f16(af[i], bf[j], acc[i][j], 0, 0, 0);
    __syncthreads();
  }

  const int rb = (lane >> 4) << 2, cb = lane & 15;
  #pragma unroll
  for (int i = 0; i < 4; i++)
    #pragma unroll
    for (int r = 0; r < 4; r++) {
      const int gm = jb + wm + (i << 4) + rb + r;               // j
      const float dg = deg[gm];
      const long eb = ((long)bb*NN + gm)*3;
      const float e0 = e_agg[eb], e1 = e_agg[eb+1], e2 = e_agg[eb+2];
      #pragma unroll
      for (int j = 0; j < 4; j++) {
        const int gn = wn + (j << 4) + cb;                      // o
        const float v = acc[i][j][r] + dg*b_msg[gn]
                      + e0*We[gn*3] + e1*We[gn*3+1] + e2*We[gn*3+2];
        msgs[((long)bb*NN + gm)*HH + gn] = f2h(v);
      }
    }
}

// ---------------------------------------------------------------------------
// gemm2: updated = relu(concat(nodeh,msgs) @ Wupd^T + b_upd), + col sums
// ---------------------------------------------------------------------------
__global__ __launch_bounds__(256) void gemm2_k(
    const f16* __restrict__ nodeh, const f16* __restrict__ msgs,
    const f16* __restrict__ Wupd, const float* __restrict__ b_upd,
    f16* __restrict__ upd, float* __restrict__ sums)
{
  const int mt = blockIdx.x;
  const int rowb = mt << 7;
  __shared__ f16 As[128*32];
  __shared__ f16 Bs[128*32];
  __shared__ float colS[128], colQ[128];
  const int tid = threadIdx.x, lane = tid & 63, wave = tid >> 6;
  const int wm = (wave & 1) << 6, wn = (wave >> 1) << 6;
  if (tid < 128) { colS[tid] = 0.f; colQ[tid] = 0.f; }

  f32x4 acc[4][4];
  #pragma unroll
  for (int i = 0; i < 4; i++)
    #pragma unroll
    for (int j = 0; j < 4; j++)
      #pragma unroll
      for (int r = 0; r < 4; r++) acc[i][j][r] = 0.f;

  for (int k0 = 0; k0 < 256; k0 += 32) {
    #pragma unroll
    for (int p = 0; p < 2; p++) {
      const int q = (p << 8) + tid;
      const int row = q >> 2, kp = (q & 3) << 3;
      const f16* src = (k0 < HH)
        ? &nodeh[(long)(rowb + row)*HH + k0 + kp]
        : &msgs[(long)(rowb + row)*HH + (k0 - HH) + kp];
      gl_lds16(src, &As[q << 3]);
      gl_lds16(&Wupd[(long)row*256 + k0 + kp], &Bs[q << 3]);
    }
    __syncthreads();
    f16x8 af[4], bf[4];
    #pragma unroll
    for (int i = 0; i < 4; i++) {
      af[i] = *(const f16x8*)&As[((wm + (i << 4) + (lane & 15)) << 5) + ((lane >> 4) << 3)];
      bf[i] = *(const f16x8*)&Bs[((wn + (i << 4) + (lane & 15)) << 5) + ((lane >> 4) << 3)];
    }
    #pragma unroll
    for (int i = 0; i < 4; i++)
      #pragma unroll
      for (int j = 0; j < 4; j++)
        acc[i][j] = __builtin_amdgcn_mfma_f32_16x16x32_f16(af[i], bf[j], acc[i][j], 0, 0, 0);
    __syncthreads();
  }

  const int rb = (lane >> 4) << 2, cb = lane & 15;
  float bup[4], s[4] = {0,0,0,0}, qq[4] = {0,0,0,0};
  #pragma unroll
  for (int j = 0; j < 4; j++) bup[j] = b_upd[wn + (j << 4) + cb];
  #pragma unroll
  for (int i = 0; i < 4; i++)
    #pragma unroll
    for (int r = 0; r < 4; r++) {
      const int gm = rowb + wm + (i << 4) + rb + r;             // flat row
      #pragma unroll
      for (int j = 0; j < 4; j++) {
        const int gn = wn + (j << 4) + cb;                      // o
        const float v = fmaxf(acc[i][j][r] + bup[j], 0.f);
        upd[(long)gm*HH + gn] = f2h(v);
        s[j] += v; qq[j] += v*v;
      }
    }
  #pragma unroll
  for (int j = 0; j < 4; j++) {
    const int gn = wn + (j << 4) + cb;
    atomicAdd(&colS[gn], s[j]);
    atomicAdd(&colQ[gn], qq[j]);
  }
  __syncthreads();
  if (tid < 128) {
    atomicAdd(&sums[tid],       colS[tid]);
    atomicAdd(&sums[128 + tid], colQ[tid]);
  }
}

// ---------------------------------------------------------------------------
__global__ __launch_bounds__(256) void final_k(const f16* __restrict__ upd,
    const float* __restrict__ node, const float* __restrict__ sums,
    const float* __restrict__ gamma, const float* __restrict__ beta,
    float* __restrict__ out)
{
  const long idx = (long)blockIdx.x*256 + threadIdx.x;   // float4 index
  const f16x4 u  = *(const f16x4*)&upd[idx << 2];
  const float4 nd = ((const float4*)node)[idx];
  const int ob = (idx & 31) << 2;
  const float inv = 1.0f/32768.0f;
  float4 res;
  #pragma unroll
  for (int c = 0; c < 4; c++) {
    const float m  = sums[ob + c]*inv;
    const float va = sums[128 + ob + c]*inv - m*m;
    const float sc = rsqrtf(va + EPS)*gamma[ob + c];
    ((float*)&res)[c] = ((float)u[c] - m)*sc + beta[ob + c]
                      + ((const float*)&nd)[c];
  }
  ((float4*)out)[idx] = res;
}

// ---------------------------------------------------------------------------
extern "C" void kernel_launch(void* const* d_in, const int* in_sizes, int n_in,
                              void* d_out, int out_size, void* d_ws, size_t ws_size,
                              hipStream_t stream) {
  const float* node  = (const float*)d_in[0];
  const float* E     = (const float*)d_in[1];
  const int*   adj   = (const int*)  d_in[2];
  const float* W_msg = (const float*)d_in[3];
  const float* b_msg = (const float*)d_in[4];
  const float* W_upd = (const float*)d_in[5];
  const float* b_upd = (const float*)d_in[6];
  const float* gamma = (const float*)d_in[7];
  const float* beta  = (const float*)d_in[8];
  float* out = (float*)d_out;

  char* p = (char*)d_ws;
  auto alloc = [&](size_t n) { void* r = (void*)p; p += (n + 255) & ~(size_t)255; return r; };
  f16*   h_part_T = (f16*)  alloc((size_t)BB*HH*NN*2);   // [b][o][i]  8 MB
  f16*   msgs     = (f16*)  alloc((size_t)ROWS*HH*2);    // [row][o]   8 MB
  f16*   upd      = (f16*)  alloc((size_t)ROWS*HH*2);    // relu out   8 MB
  f16*   nodeh    = (f16*)  alloc((size_t)ROWS*HH*2);    // node f16   8 MB
  f16*   maskf    = (f16*)  alloc((size_t)NN*NN*2);      // mask[j][i] 2 MB
  f16*   maskT    = (f16*)  alloc((size_t)NN*NN*2);      // mask[j][i]^T 2 MB
  float* e_agg    = (float*)alloc((size_t)BB*NN*3*4);    // 384 KB
  f16*   Wh       = (f16*)  alloc((size_t)HH*HH*2);
  f16*   Wupd     = (f16*)  alloc((size_t)HH*256*2);
  float* We       = (float*)alloc((size_t)HH*3*4);
  float* deg      = (float*)alloc((size_t)NN*4);
  float* sums     = (float*)alloc((size_t)256*4);

  prep0_k<<<79, 256, 0, stream>>>(W_msg, W_upd, node, adj,
                                  Wh, Wupd, We, e_agg, deg, sums,
                                  nodeh, maskf, maskT);

  phaseB_k<<<1280, 256, 0, stream>>>(nodeh, E, maskT, Wh, h_part_T, e_agg);

  gemm1_k<<<dim3(8, 1, BB), 256, 0, stream>>>(maskf, h_part_T, deg, b_msg, e_agg, We, msgs);

  gemm2_k<<<256, 256, 0, stream>>>(nodeh, msgs, Wupd, b_upd, upd, sums);

  final_k<<<4096, 256, 0, stream>>>(upd, node, sums, gamma, beta, out);
}

// Round 2
// 643.193 us; speedup vs baseline: 1.0736x; 1.0736x over previous
//
#include <hip/hip_runtime.h>

typedef _Float16 f16;
typedef f16 f16x4 __attribute__((ext_vector_type(4)));
typedef f16 f16x8 __attribute__((ext_vector_type(8)));
typedef float f32x4 __attribute__((ext_vector_type(4)));

#define BB 32
#define NN 1024
#define HH 128
#define ROWS (BB*NN)          // 32768
#define EPS 1e-5f

__device__ __forceinline__ f16 f2h(float x) { return (f16)x; }

typedef __attribute__((address_space(1))) const void gv_t;
typedef __attribute__((address_space(3))) void lv_t;
__device__ __forceinline__ void gl_lds16(const void* g, void* l) {
  __builtin_amdgcn_global_load_lds((gv_t*)g, (lv_t*)l, 16, 0, 0);
}

// ---------------------------------------------------------------------------
// prep0: pack/convert kernel (131 blocks x 256) — all paths parallel.
//  blk 0..63   : node f32 -> f16 (nodeh), 256KB each
//  blk 64..127 : adj 128x128 tile -> maskf (identity) + maskT (transpose)
//  blk 128     : Wh f16[128][128] from W_msg (stride 131)
//  blk 129     : Wupd f16[128][256]
//  blk 130     : We f32[128][3]
// ---------------------------------------------------------------------------
__global__ __launch_bounds__(256) void prep0_k(
    const float* __restrict__ W_msg, const float* __restrict__ W_upd,
    const float* __restrict__ node, const int* __restrict__ adj,
    f16* __restrict__ Wh, f16* __restrict__ Wupd, float* __restrict__ We,
    f16* __restrict__ nodeh, f16* __restrict__ maskf, f16* __restrict__ maskT)
{
  const int blk = blockIdx.x, t = threadIdx.x;
  if (blk < 64) {
    // node -> f16, flat float4 space: 16384 float4 per block
    const long base = (long)blk*16384 + t;
    #pragma unroll
    for (int p = 0; p < 64; p++) {
      const long idx = base + (long)p*256;
      const float4 v = ((const float4*)node)[idx];
      f16x4 hv; hv[0] = f2h(v.x); hv[1] = f2h(v.y); hv[2] = f2h(v.z); hv[3] = f2h(v.w);
      *(f16x4*)&nodeh[idx << 2] = hv;
    }
  } else if (blk < 128) {
    // adj tile (tj,ti) 128x128: coalesced int4 read -> maskf write + LDS
    // transpose -> coalesced maskT write.
    __shared__ f16 ldsT[128][136];     // [i_local][j_local], padded
    const int tt = blk - 64, tj = tt >> 3, ti = tt & 7;
    #pragma unroll
    for (int p = 0; p < 16; p++) {
      const int q = p*256 + t;
      const int row = q >> 5, c4 = (q & 31) << 2;
      const int4 m = *(const int4*)&adj[(long)(tj*128 + row)*NN + ti*128 + c4];
      f16x4 hv;
      hv[0] = (m.x > 0) ? (f16)1.0f : (f16)0.0f;
      hv[1] = (m.y > 0) ? (f16)1.0f : (f16)0.0f;
      hv[2] = (m.z > 0) ? (f16)1.0f : (f16)0.0f;
      hv[3] = (m.w > 0) ? (f16)1.0f : (f16)0.0f;
      *(f16x4*)&maskf[(long)(tj*128 + row)*NN + ti*128 + c4] = hv;
      ldsT[c4 + 0][row] = hv[0];
      ldsT[c4 + 1][row] = hv[1];
      ldsT[c4 + 2][row] = hv[2];
      ldsT[c4 + 3][row] = hv[3];
    }
    __syncthreads();
    #pragma unroll
    for (int p = 0; p < 8; p++) {
      const int q = p*256 + t;
      const int rT = q >> 4, c8 = (q & 15) << 3;
      *(uint4*)&maskT[(long)(ti*128 + rT)*NN + tj*128 + c8] =
          *(const uint4*)&ldsT[rT][c8];
    }
  } else if (blk == 128) {
    for (int idx = t; idx < HH*HH; idx += 256) {
      const int o = idx >> 7, h = idx & 127;
      Wh[idx] = f2h(W_msg[o*131 + h]);
    }
  } else if (blk == 129) {
    for (int idx = t; idx < HH*256; idx += 256)
      Wupd[idx] = f2h(W_upd[idx]);
  } else {
    for (int idx = t; idx < HH*3; idx += 256)
      We[idx] = W_msg[(idx/3)*131 + 128 + (idx % 3)];
  }
}

// ---------------------------------------------------------------------------
// Phase B megakernel: 1280 blocks x 256.
//  blk [0,256): gemm0 — h_part_T[b][o][i] = sum_h Wh[o][h]*nodeh[b,i,h] + b_msg[o]
//               (b_msg folded here: msg_h + deg*b_msg = mask @ (h_part + b_msg))
//  blk [256,1280): eagg — e_agg[b][j][c] += sum_i E[b,i,j,c]*maskT[i][j]
//               E staged via coalesced global_load_lds (24KB per 8-i chunk).
// ---------------------------------------------------------------------------
__global__ __launch_bounds__(256) void phaseB_k(
    const f16* __restrict__ nodeh, const float* __restrict__ E,
    const f16* __restrict__ maskT, const f16* __restrict__ Wh,
    const float* __restrict__ b_msg,
    f16* __restrict__ h_part_T, float* __restrict__ e_agg)
{
  __shared__ __align__(16) char smem[24576];
  const int tid = threadIdx.x;

  if (blockIdx.x >= 256) {
    // ---- eagg path ----
    float* Ebuf = (float*)smem;             // [8][768]
    const int e  = blockIdx.x - 256;        // 0..1023
    const int bb = e >> 5;
    const int r5 = e & 31;
    const int jt = r5 & 3;                  // 4 j-tiles of 256
    const int ih = r5 >> 2;                 // 8 i-chunks of 128
    const int j  = (jt << 8) + tid;
    const int i0 = ih << 7;
    const int lane = tid & 63, wv = tid >> 6;
    const float* Eblk = E + (long)bb*3145728 + (long)i0*3072 + (long)(jt << 8)*3;
    float a0 = 0.f, a1 = 0.f, a2 = 0.f;
    for (int ch = 0; ch < 16; ch++) {
      const float* Ech = Eblk + (long)ch*8*3072;
      __syncthreads();                      // buffer reuse fence
      #pragma unroll
      for (int k = 0; k < 6; k++) {
        const int m = wv*6 + k;             // 0..23, wave-uniform
        const int r = m/3;
        const int cb = (m % 3) << 8;        // 256 floats = 1KB
        gl_lds16(Ech + (long)r*3072 + cb + lane*4, Ebuf + m*256);
      }
      float mreg[8];
      #pragma unroll
      for (int v = 0; v < 8; v++)
        mreg[v] = (float)maskT[(long)(i0 + ch*8 + v)*NN + j];
      __syncthreads();                      // drains vmcnt: E + masks ready
      #pragma unroll
      for (int v = 0; v < 8; v++) {
        const float e0 = Ebuf[v*768 + tid*3];
        const float e1 = Ebuf[v*768 + tid*3 + 1];
        const float e2 = Ebuf[v*768 + tid*3 + 2];
        a0 = fmaf(mreg[v], e0, a0);
        a1 = fmaf(mreg[v], e1, a1);
        a2 = fmaf(mreg[v], e2, a2);
      }
    }
    const long eb = ((long)bb*NN + j)*3;
    atomicAdd(&e_agg[eb],     a0);
    atomicAdd(&e_agg[eb + 1], a1);
    atomicAdd(&e_agg[eb + 2], a2);
    return;
  }

  // ---- gemm0 path: M=128 (o), N=128 tile (i), K=128, gl_lds staging ----
  f16* As = (f16*)smem;                     // 128x32
  f16* Bs = (f16*)(smem + 8192);            // 128x32
  const int g  = blockIdx.x;
  const int nt = g & 7, bb = g >> 3;
  const int nbase = nt << 7;
  const int lane = tid & 63, wave = tid >> 6;
  const int wm = (wave & 1) << 6, wn = (wave >> 1) << 6;

  f32x4 acc[2][4], acc2[2][4];
  #pragma unroll
  for (int i = 0; i < 2; i++)
    #pragma unroll
    for (int j = 0; j < 4; j++)
      #pragma unroll
      for (int r = 0; r < 4; r++) { acc[i][j][r] = 0.f; acc2[i][j][r] = 0.f; }

  for (int k0 = 0; k0 < HH; k0 += 32) {
    #pragma unroll
    for (int p = 0; p < 2; p++) {
      const int q = (p << 8) + tid;
      const int row = q >> 2, kp = (q & 3) << 3;
      gl_lds16(&Wh[(long)row*HH + k0 + kp], &As[q << 3]);
      gl_lds16(&nodeh[(long)((bb << 10) + nbase + row)*HH + k0 + kp], &Bs[q << 3]);
    }
    __syncthreads();
    f16x8 af[4], bf[4];
    #pragma unroll
    for (int i = 0; i < 4; i++) {
      af[i] = *(const f16x8*)&As[((wm + (i << 4) + (lane & 15)) << 5) + ((lane >> 4) << 3)];
      bf[i] = *(const f16x8*)&Bs[((wn + (i << 4) + (lane & 15)) << 5) + ((lane >> 4) << 3)];
    }
    #pragma unroll
    for (int i = 0; i < 2; i++)
      #pragma unroll
      for (int j = 0; j < 4; j++) {
        acc[i][j]  = __builtin_amdgcn_mfma_f32_16x16x32_f16(af[i],     bf[j], acc[i][j],  0, 0, 0);
        acc2[i][j] = __builtin_amdgcn_mfma_f32_16x16x32_f16(af[i + 2], bf[j], acc2[i][j], 0, 0, 0);
      }
    __syncthreads();
  }

  f16* out = h_part_T + (long)bb * (HH*NN);
  const int rb = (lane >> 4) << 2, cb = lane & 15;
  #pragma unroll
  for (int i = 0; i < 4; i++)
    #pragma unroll
    for (int r = 0; r < 4; r++) {
      const int gm = wm + (i << 4) + rb + r;                    // o
      const float bm = b_msg[gm];
      #pragma unroll
      for (int j = 0; j < 4; j++) {
        const int gn = nbase + wn + (j << 4) + cb;              // i
        const float v = ((i < 2) ? acc[i][j][r] : acc2[i - 2][j][r]) + bm;
        out[(long)gm*NN + gn] = f2h(v);
      }
    }
}

// ---------------------------------------------------------------------------
// gemm1: messages[b,j,o] = sum_i maskf[j,i]*h_part_T[b][o][i]
//        + e_agg[b,j,:]·We[o,:]   (deg*b_msg folded into h_part_T)
// ---------------------------------------------------------------------------
__global__ __launch_bounds__(256) void gemm1_k(
    const f16* __restrict__ maskf, const f16* __restrict__ hp,
    const float* __restrict__ e_agg, const float* __restrict__ We,
    f16* __restrict__ msgs)
{
  const int mt = blockIdx.x, bb = blockIdx.z;
  const int jb = mt << 7;
  __shared__ f16 As[128*32];
  __shared__ f16 Bs[128*32];
  const int tid = threadIdx.x, lane = tid & 63, wave = tid >> 6;
  const int wm = (wave & 1) << 6, wn = (wave >> 1) << 6;

  f32x4 acc[4][4];
  #pragma unroll
  for (int i = 0; i < 4; i++)
    #pragma unroll
    for (int j = 0; j < 4; j++)
      #pragma unroll
      for (int r = 0; r < 4; r++) acc[i][j][r] = 0.f;

  for (int k0 = 0; k0 < NN; k0 += 32) {
    #pragma unroll
    for (int p = 0; p < 2; p++) {
      const int q = (p << 8) + tid;
      const int row = q >> 2, kp = (q & 3) << 3;
      gl_lds16(&maskf[(long)(jb + row)*NN + k0 + kp], &As[q << 3]);
      gl_lds16(&hp[(long)bb*(HH*NN) + (long)row*NN + k0 + kp], &Bs[q << 3]);
    }
    __syncthreads();
    f16x8 af[4], bf[4];
    #pragma unroll
    for (int i = 0; i < 4; i++) {
      af[i] = *(const f16x8*)&As[((wm + (i << 4) + (lane & 15)) << 5) + ((lane >> 4) << 3)];
      bf[i] = *(const f16x8*)&Bs[((wn + (i << 4) + (lane & 15)) << 5) + ((lane >> 4) << 3)];
    }
    #pragma unroll
    for (int i = 0; i < 4; i++)
      #pragma unroll
      for (int j = 0; j < 4; j++)
        acc[i][j] = __builtin_amdgcn_mfma_f32_16x16x32_f16(af[i], bf[j], acc[i][j], 0, 0, 0);
    __syncthreads();
  }

  const int rb = (lane >> 4) << 2, cb = lane & 15;
  #pragma unroll
  for (int i = 0; i < 4; i++)
    #pragma unroll
    for (int r = 0; r < 4; r++) {
      const int gm = jb + wm + (i << 4) + rb + r;               // j
      const long eb = ((long)bb*NN + gm)*3;
      const float e0 = e_agg[eb], e1 = e_agg[eb+1], e2 = e_agg[eb+2];
      #pragma unroll
      for (int j = 0; j < 4; j++) {
        const int gn = wn + (j << 4) + cb;                      // o
        const float v = acc[i][j][r]
                      + e0*We[gn*3] + e1*We[gn*3+1] + e2*We[gn*3+2];
        msgs[((long)bb*NN + gm)*HH + gn] = f2h(v);
      }
    }
}

// ---------------------------------------------------------------------------
// gemm2: updated = relu(concat(nodeh,msgs) @ Wupd^T + b_upd), + col sums
// ---------------------------------------------------------------------------
__global__ __launch_bounds__(256) void gemm2_k(
    const f16* __restrict__ nodeh, const f16* __restrict__ msgs,
    const f16* __restrict__ Wupd, const float* __restrict__ b_upd,
    f16* __restrict__ upd, float* __restrict__ sums)
{
  const int mt = blockIdx.x;
  const int rowb = mt << 7;
  __shared__ f16 As[128*32];
  __shared__ f16 Bs[128*32];
  __shared__ float colS[128], colQ[128];
  const int tid = threadIdx.x, lane = tid & 63, wave = tid >> 6;
  const int wm = (wave & 1) << 6, wn = (wave >> 1) << 6;
  if (tid < 128) { colS[tid] = 0.f; colQ[tid] = 0.f; }

  f32x4 acc[4][4];
  #pragma unroll
  for (int i = 0; i < 4; i++)
    #pragma unroll
    for (int j = 0; j < 4; j++)
      #pragma unroll
      for (int r = 0; r < 4; r++) acc[i][j][r] = 0.f;

  for (int k0 = 0; k0 < 256; k0 += 32) {
    #pragma unroll
    for (int p = 0; p < 2; p++) {
      const int q = (p << 8) + tid;
      const int row = q >> 2, kp = (q & 3) << 3;
      const f16* src = (k0 < HH)
        ? &nodeh[(long)(rowb + row)*HH + k0 + kp]
        : &msgs[(long)(rowb + row)*HH + (k0 - HH) + kp];
      gl_lds16(src, &As[q << 3]);
      gl_lds16(&Wupd[(long)row*256 + k0 + kp], &Bs[q << 3]);
    }
    __syncthreads();
    f16x8 af[4], bf[4];
    #pragma unroll
    for (int i = 0; i < 4; i++) {
      af[i] = *(const f16x8*)&As[((wm + (i << 4) + (lane & 15)) << 5) + ((lane >> 4) << 3)];
      bf[i] = *(const f16x8*)&Bs[((wn + (i << 4) + (lane & 15)) << 5) + ((lane >> 4) << 3)];
    }
    #pragma unroll
    for (int i = 0; i < 4; i++)
      #pragma unroll
      for (int j = 0; j < 4; j++)
        acc[i][j] = __builtin_amdgcn_mfma_f32_16x16x32_f16(af[i], bf[j], acc[i][j], 0, 0, 0);
    __syncthreads();
  }

  const int rb = (lane >> 4) << 2, cb = lane & 15;
  float bup[4], s[4] = {0,0,0,0}, qq[4] = {0,0,0,0};
  #pragma unroll
  for (int j = 0; j < 4; j++) bup[j] = b_upd[wn + (j << 4) + cb];
  #pragma unroll
  for (int i = 0; i < 4; i++)
    #pragma unroll
    for (int r = 0; r < 4; r++) {
      const int gm = rowb + wm + (i << 4) + rb + r;             // flat row
      #pragma unroll
      for (int j = 0; j < 4; j++) {
        const int gn = wn + (j << 4) + cb;                      // o
        const float v = fmaxf(acc[i][j][r] + bup[j], 0.f);
        upd[(long)gm*HH + gn] = f2h(v);
        s[j] += v; qq[j] += v*v;
      }
    }
  #pragma unroll
  for (int j = 0; j < 4; j++) {
    const int gn = wn + (j << 4) + cb;
    atomicAdd(&colS[gn], s[j]);
    atomicAdd(&colQ[gn], qq[j]);
  }
  __syncthreads();
  if (tid < 128) {
    atomicAdd(&sums[tid],       colS[tid]);
    atomicAdd(&sums[128 + tid], colQ[tid]);
  }
}

// ---------------------------------------------------------------------------
__global__ __launch_bounds__(256) void final_k(const f16* __restrict__ upd,
    const float* __restrict__ node, const float* __restrict__ sums,
    const float* __restrict__ gamma, const float* __restrict__ beta,
    float* __restrict__ out)
{
  const long idx = (long)blockIdx.x*256 + threadIdx.x;   // float4 index
  const f16x4 u  = *(const f16x4*)&upd[idx << 2];
  const float4 nd = ((const float4*)node)[idx];
  const int ob = (idx & 31) << 2;
  const float inv = 1.0f/32768.0f;
  float4 res;
  #pragma unroll
  for (int c = 0; c < 4; c++) {
    const float m  = sums[ob + c]*inv;
    const float va = sums[128 + ob + c]*inv - m*m;
    const float sc = rsqrtf(va + EPS)*gamma[ob + c];
    ((float*)&res)[c] = ((float)u[c] - m)*sc + beta[ob + c]
                      + ((const float*)&nd)[c];
  }
  ((float4*)out)[idx] = res;
}

// ---------------------------------------------------------------------------
extern "C" void kernel_launch(void* const* d_in, const int* in_sizes, int n_in,
                              void* d_out, int out_size, void* d_ws, size_t ws_size,
                              hipStream_t stream) {
  const float* node  = (const float*)d_in[0];
  const float* E     = (const float*)d_in[1];
  const int*   adj   = (const int*)  d_in[2];
  const float* W_msg = (const float*)d_in[3];
  const float* b_msg = (const float*)d_in[4];
  const float* W_upd = (const float*)d_in[5];
  const float* b_upd = (const float*)d_in[6];
  const float* gamma = (const float*)d_in[7];
  const float* beta  = (const float*)d_in[8];
  float* out = (float*)d_out;

  char* p = (char*)d_ws;
  auto alloc = [&](size_t n) { void* r = (void*)p; p += (n + 255) & ~(size_t)255; return r; };
  f16*   h_part_T = (f16*)  alloc((size_t)BB*HH*NN*2);   // [b][o][i]  8 MB
  f16*   msgs     = (f16*)  alloc((size_t)ROWS*HH*2);    // [row][o]   8 MB
  f16*   upd      = (f16*)  alloc((size_t)ROWS*HH*2);    // relu out   8 MB
  f16*   nodeh    = (f16*)  alloc((size_t)ROWS*HH*2);    // node f16   8 MB
  f16*   maskf    = (f16*)  alloc((size_t)NN*NN*2);      // mask[j][i] 2 MB
  f16*   maskT    = (f16*)  alloc((size_t)NN*NN*2);      // mask[i][j] 2 MB
  float* e_agg    = (float*)alloc((size_t)BB*NN*3*4);    // 384 KB
  f16*   Wh       = (f16*)  alloc((size_t)HH*HH*2);
  f16*   Wupd     = (f16*)  alloc((size_t)HH*256*2);
  float* We       = (float*)alloc((size_t)HH*3*4);
  float* sums     = (float*)alloc((size_t)256*4);

  hipMemsetAsync(e_agg, 0, (size_t)BB*NN*3*4, stream);
  hipMemsetAsync(sums,  0, (size_t)256*4, stream);

  prep0_k<<<131, 256, 0, stream>>>(W_msg, W_upd, node, adj,
                                   Wh, Wupd, We, nodeh, maskf, maskT);

  phaseB_k<<<1280, 256, 0, stream>>>(nodeh, E, maskT, Wh, b_msg, h_part_T, e_agg);

  gemm1_k<<<dim3(8, 1, BB), 256, 0, stream>>>(maskf, h_part_T, e_agg, We, msgs);

  gemm2_k<<<256, 256, 0, stream>>>(nodeh, msgs, Wupd, b_upd, upd, sums);

  final_k<<<4096, 256, 0, stream>>>(upd, node, sums, gamma, beta, out);
}

// Round 3
// 630.711 us; speedup vs baseline: 1.0948x; 1.0198x over previous
//
#include <hip/hip_runtime.h>

typedef _Float16 f16;
typedef f16 f16x4 __attribute__((ext_vector_type(4)));
typedef f16 f16x8 __attribute__((ext_vector_type(8)));
typedef float f32x4 __attribute__((ext_vector_type(4)));

#define BB 32
#define NN 1024
#define HH 128
#define ROWS (BB*NN)          // 32768
#define EPS 1e-5f

__device__ __forceinline__ f16 f2h(float x) { return (f16)x; }

typedef __attribute__((address_space(1))) const void gv_t;
typedef __attribute__((address_space(3))) void lv_t;
__device__ __forceinline__ void gl_lds16(const void* g, void* l) {
  __builtin_amdgcn_global_load_lds((gv_t*)g, (lv_t*)l, 16, 0, 0);
}

// ---------------------------------------------------------------------------
// prep0 (135 blocks x 256) — all paths parallel, zeroing folded in.
//  blk 0..63   : node f32 -> f16 (nodeh)
//  blk 64..127 : adj 128x128 tile -> maskf (identity) + maskT (transpose)
//  blk 128     : Wh f16[128][128] from W_msg (stride 131)
//  blk 129     : Wupd f16[128][256]
//  blk 130     : We f32[128][3] + zero sums[256]
//  blk 131..134: zero e_agg
// ---------------------------------------------------------------------------
__global__ __launch_bounds__(256) void prep0_k(
    const float* __restrict__ W_msg, const float* __restrict__ W_upd,
    const float* __restrict__ node, const int* __restrict__ adj,
    f16* __restrict__ Wh, f16* __restrict__ Wupd, float* __restrict__ We,
    f16* __restrict__ nodeh, f16* __restrict__ maskf, f16* __restrict__ maskT,
    float* __restrict__ e_agg, float* __restrict__ sums)
{
  const int blk = blockIdx.x, t = threadIdx.x;
  if (blk < 64) {
    const long base = (long)blk*16384 + t;
    #pragma unroll
    for (int p = 0; p < 64; p++) {
      const long idx = base + (long)p*256;
      const float4 v = ((const float4*)node)[idx];
      f16x4 hv; hv[0] = f2h(v.x); hv[1] = f2h(v.y); hv[2] = f2h(v.z); hv[3] = f2h(v.w);
      *(f16x4*)&nodeh[idx << 2] = hv;
    }
  } else if (blk < 128) {
    __shared__ f16 ldsT[128][136];     // [i_local][j_local], padded
    const int tt = blk - 64, tj = tt >> 3, ti = tt & 7;
    #pragma unroll
    for (int p = 0; p < 16; p++) {
      const int q = p*256 + t;
      const int row = q >> 5, c4 = (q & 31) << 2;
      const int4 m = *(const int4*)&adj[(long)(tj*128 + row)*NN + ti*128 + c4];
      f16x4 hv;
      hv[0] = (m.x > 0) ? (f16)1.0f : (f16)0.0f;
      hv[1] = (m.y > 0) ? (f16)1.0f : (f16)0.0f;
      hv[2] = (m.z > 0) ? (f16)1.0f : (f16)0.0f;
      hv[3] = (m.w > 0) ? (f16)1.0f : (f16)0.0f;
      *(f16x4*)&maskf[(long)(tj*128 + row)*NN + ti*128 + c4] = hv;
      ldsT[c4 + 0][row] = hv[0];
      ldsT[c4 + 1][row] = hv[1];
      ldsT[c4 + 2][row] = hv[2];
      ldsT[c4 + 3][row] = hv[3];
    }
    __syncthreads();
    #pragma unroll
    for (int p = 0; p < 8; p++) {
      const int q = p*256 + t;
      const int rT = q >> 4, c8 = (q & 15) << 3;
      *(uint4*)&maskT[(long)(ti*128 + rT)*NN + tj*128 + c8] =
          *(const uint4*)&ldsT[rT][c8];
    }
  } else if (blk == 128) {
    for (int idx = t; idx < HH*HH; idx += 256) {
      const int o = idx >> 7, h = idx & 127;
      Wh[idx] = f2h(W_msg[o*131 + h]);
    }
  } else if (blk == 129) {
    for (int idx = t; idx < HH*256; idx += 256)
      Wupd[idx] = f2h(W_upd[idx]);
  } else if (blk == 130) {
    for (int idx = t; idx < HH*3; idx += 256)
      We[idx] = W_msg[(idx/3)*131 + 128 + (idx % 3)];
    if (t < 256) sums[t] = 0.f;
  } else {
    const int base = (blk - 131) * 24576 + t;
    #pragma unroll
    for (int r = 0; r < 96; r++) e_agg[base + r*256] = 0.f;
  }
}

// ---------------------------------------------------------------------------
// Phase B megakernel: 2304 blocks x 256.
//  blk [0,256): gemm0 — h_part_T[b][o][i] = sum_h Wh[o][h]*nodeh[b,i,h] + b_msg[o]
//  blk [256,2304): eagg (2048 blocks, 64 i-rows each, 8 chunks of 8 rows):
//     e_agg[b][j][c] += sum_i E[b,i,j,c]*maskT[i][j]
//     6 resident blocks/CU hide the per-chunk vmcnt drain via block TLP.
// ---------------------------------------------------------------------------
__global__ __launch_bounds__(256) void phaseB_k(
    const f16* __restrict__ nodeh, const float* __restrict__ E,
    const f16* __restrict__ maskT, const f16* __restrict__ Wh,
    const float* __restrict__ b_msg,
    f16* __restrict__ h_part_T, float* __restrict__ e_agg)
{
  __shared__ __align__(16) char smem[24576];
  const int tid = threadIdx.x;

  if (blockIdx.x >= 256) {
    // ---- eagg path ----
    float* Ebuf = (float*)smem;             // [8][768]
    const int e  = blockIdx.x - 256;        // 0..2047
    const int bb = e >> 6;
    const int r6 = e & 63;
    const int jt = r6 & 3;                  // 4 j-tiles of 256
    const int ih = r6 >> 2;                 // 16 i-chunks of 64
    const int j  = (jt << 8) + tid;
    const int i0 = ih << 6;
    const int lane = tid & 63, wv = tid >> 6;
    const float* Eblk = E + (long)bb*3145728 + (long)i0*3072 + (long)(jt << 8)*3;
    float a0 = 0.f, a1 = 0.f, a2 = 0.f;
    for (int ch = 0; ch < 8; ch++) {
      const float* Ech = Eblk + (long)ch*8*3072;
      __syncthreads();                      // buffer reuse fence
      #pragma unroll
      for (int k = 0; k < 6; k++) {
        const int m = wv*6 + k;             // 0..23, wave-uniform
        const int r = m/3;
        const int cb = (m % 3) << 8;        // 256 floats = 1KB
        gl_lds16(Ech + (long)r*3072 + cb + lane*4, Ebuf + m*256);
      }
      float mreg[8];
      #pragma unroll
      for (int v = 0; v < 8; v++)
        mreg[v] = (float)maskT[(long)(i0 + ch*8 + v)*NN + j];
      __syncthreads();                      // drains vmcnt: E + masks ready
      #pragma unroll
      for (int v = 0; v < 8; v++) {
        const float e0 = Ebuf[v*768 + tid*3];
        const float e1 = Ebuf[v*768 + tid*3 + 1];
        const float e2 = Ebuf[v*768 + tid*3 + 2];
        a0 = fmaf(mreg[v], e0, a0);
        a1 = fmaf(mreg[v], e1, a1);
        a2 = fmaf(mreg[v], e2, a2);
      }
    }
    const long eb = ((long)bb*NN + j)*3;
    atomicAdd(&e_agg[eb],     a0);
    atomicAdd(&e_agg[eb + 1], a1);
    atomicAdd(&e_agg[eb + 2], a2);
    return;
  }

  // ---- gemm0 path: M=128 (o), N=128 tile (i), K=128, gl_lds staging ----
  f16* As = (f16*)smem;                     // 128x32
  f16* Bs = (f16*)(smem + 8192);            // 128x32
  const int g  = blockIdx.x;
  const int nt = g & 7, bb = g >> 3;
  const int nbase = nt << 7;
  const int lane = tid & 63, wave = tid >> 6;
  const int wm = (wave & 1) << 6, wn = (wave >> 1) << 6;

  f32x4 acc[2][4], acc2[2][4];
  #pragma unroll
  for (int i = 0; i < 2; i++)
    #pragma unroll
    for (int j = 0; j < 4; j++)
      #pragma unroll
      for (int r = 0; r < 4; r++) { acc[i][j][r] = 0.f; acc2[i][j][r] = 0.f; }

  for (int k0 = 0; k0 < HH; k0 += 32) {
    #pragma unroll
    for (int p = 0; p < 2; p++) {
      const int q = (p << 8) + tid;
      const int row = q >> 2, kp = (q & 3) << 3;
      gl_lds16(&Wh[(long)row*HH + k0 + kp], &As[q << 3]);
      gl_lds16(&nodeh[(long)((bb << 10) + nbase + row)*HH + k0 + kp], &Bs[q << 3]);
    }
    __syncthreads();
    f16x8 af[4], bf[4];
    #pragma unroll
    for (int i = 0; i < 4; i++) {
      af[i] = *(const f16x8*)&As[((wm + (i << 4) + (lane & 15)) << 5) + ((lane >> 4) << 3)];
      bf[i] = *(const f16x8*)&Bs[((wn + (i << 4) + (lane & 15)) << 5) + ((lane >> 4) << 3)];
    }
    #pragma unroll
    for (int i = 0; i < 2; i++)
      #pragma unroll
      for (int j = 0; j < 4; j++) {
        acc[i][j]  = __builtin_amdgcn_mfma_f32_16x16x32_f16(af[i],     bf[j], acc[i][j],  0, 0, 0);
        acc2[i][j] = __builtin_amdgcn_mfma_f32_16x16x32_f16(af[i + 2], bf[j], acc2[i][j], 0, 0, 0);
      }
    __syncthreads();
  }

  f16* out = h_part_T + (long)bb * (HH*NN);
  const int rb = (lane >> 4) << 2, cb = lane & 15;
  #pragma unroll
  for (int i = 0; i < 4; i++)
    #pragma unroll
    for (int r = 0; r < 4; r++) {
      const int gm = wm + (i << 4) + rb + r;                    // o
      const float bm = b_msg[gm];
      #pragma unroll
      for (int j = 0; j < 4; j++) {
        const int gn = nbase + wn + (j << 4) + cb;              // i
        const float v = ((i < 2) ? acc[i][j][r] : acc2[i - 2][j][r]) + bm;
        out[(long)gm*NN + gn] = f2h(v);
      }
    }
}

// ---------------------------------------------------------------------------
// gemm12 (fused): per block (mt, bb):
//  phase 1: msgs[j,o] = sum_i maskf[j,i]*hp[b][o][i] + e_agg·We  -> LDS (swizzled)
//  phase 2: updated = relu(concat(nodeh,msgs_lds) @ Wupd^T + b_upd) -> upd + sums
// ---------------------------------------------------------------------------
__global__ __launch_bounds__(256) void gemm12_k(
    const f16* __restrict__ maskf, const f16* __restrict__ hp,
    const float* __restrict__ e_agg, const float* __restrict__ We,
    const f16* __restrict__ nodeh, const f16* __restrict__ Wupd,
    const float* __restrict__ b_upd,
    f16* __restrict__ upd, float* __restrict__ sums)
{
  const int mt = blockIdx.x, bb = blockIdx.z;
  const int jb = mt << 7;                   // local j base
  const long rowb = (long)bb*NN + jb;       // flat row base
  __shared__ f16 As[128*32];
  __shared__ f16 Bs[128*32];
  __shared__ __align__(16) char msgs_lds[128*128*2];   // 32 KB, XOR-swizzled
  __shared__ float colS[128], colQ[128];
  const int tid = threadIdx.x, lane = tid & 63, wave = tid >> 6;
  const int wm = (wave & 1) << 6, wn = (wave >> 1) << 6;
  if (tid < 128) { colS[tid] = 0.f; colQ[tid] = 0.f; }
  const int rb = (lane >> 4) << 2, cb = lane & 15;

  // ---------------- phase 1: messages ----------------
  f32x4 acc[4][4];
  #pragma unroll
  for (int i = 0; i < 4; i++)
    #pragma unroll
    for (int j = 0; j < 4; j++)
      #pragma unroll
      for (int r = 0; r < 4; r++) acc[i][j][r] = 0.f;

  for (int k0 = 0; k0 < NN; k0 += 32) {
    #pragma unroll
    for (int p = 0; p < 2; p++) {
      const int q = (p << 8) + tid;
      const int row = q >> 2, kp = (q & 3) << 3;
      gl_lds16(&maskf[(long)(jb + row)*NN + k0 + kp], &As[q << 3]);
      gl_lds16(&hp[(long)bb*(HH*NN) + (long)row*NN + k0 + kp], &Bs[q << 3]);
    }
    __syncthreads();
    f16x8 af[4], bf[4];
    #pragma unroll
    for (int i = 0; i < 4; i++) {
      af[i] = *(const f16x8*)&As[((wm + (i << 4) + (lane & 15)) << 5) + ((lane >> 4) << 3)];
      bf[i] = *(const f16x8*)&Bs[((wn + (i << 4) + (lane & 15)) << 5) + ((lane >> 4) << 3)];
    }
    #pragma unroll
    for (int i = 0; i < 4; i++)
      #pragma unroll
      for (int j = 0; j < 4; j++)
        acc[i][j] = __builtin_amdgcn_mfma_f32_16x16x32_f16(af[i], bf[j], acc[i][j], 0, 0, 0);
    __syncthreads();
  }

  // epilogue 1: add e_agg·We, write msgs tile to swizzled LDS
  #pragma unroll
  for (int i = 0; i < 4; i++)
    #pragma unroll
    for (int r = 0; r < 4; r++) {
      const int lrow = wm + (i << 4) + rb + r;                  // local j
      const long eb = (rowb + lrow)*3;
      const float e0 = e_agg[eb], e1 = e_agg[eb+1], e2 = e_agg[eb+2];
      #pragma unroll
      for (int j = 0; j < 4; j++) {
        const int col = wn + (j << 4) + cb;                     // o
        const float v = acc[i][j][r]
                      + e0*We[col*3] + e1*We[col*3+1] + e2*We[col*3+2];
        const int byte = ((lrow << 8) + (col << 1)) ^ ((lrow & 7) << 4);
        *(f16*)(msgs_lds + byte) = f2h(v);
      }
    }
  __syncthreads();

  // ---------------- phase 2: update GEMM ----------------
  f32x4 acc2[4][4];
  #pragma unroll
  for (int i = 0; i < 4; i++)
    #pragma unroll
    for (int j = 0; j < 4; j++)
      #pragma unroll
      for (int r = 0; r < 4; r++) acc2[i][j][r] = 0.f;

  for (int k0 = 0; k0 < 256; k0 += 32) {
    const bool fromA = (k0 < HH);
    #pragma unroll
    for (int p = 0; p < 2; p++) {
      const int q = (p << 8) + tid;
      const int row = q >> 2, kp = (q & 3) << 3;
      if (fromA)
        gl_lds16(&nodeh[(rowb + row)*HH + k0 + kp], &As[q << 3]);
      gl_lds16(&Wupd[(long)row*256 + k0 + kp], &Bs[q << 3]);
    }
    __syncthreads();
    f16x8 af[4], bf[4];
    #pragma unroll
    for (int i = 0; i < 4; i++) {
      if (fromA) {
        af[i] = *(const f16x8*)&As[((wm + (i << 4) + (lane & 15)) << 5) + ((lane >> 4) << 3)];
      } else {
        const int lrow = wm + (i << 4) + (lane & 15);
        const int byte = ((lrow << 8) + (((k0 - HH) + ((lane >> 4) << 3)) << 1))
                         ^ ((lrow & 7) << 4);
        af[i] = *(const f16x8*)(msgs_lds + byte);
      }
      bf[i] = *(const f16x8*)&Bs[((wn + (i << 4) + (lane & 15)) << 5) + ((lane >> 4) << 3)];
    }
    #pragma unroll
    for (int i = 0; i < 4; i++)
      #pragma unroll
      for (int j = 0; j < 4; j++)
        acc2[i][j] = __builtin_amdgcn_mfma_f32_16x16x32_f16(af[i], bf[j], acc2[i][j], 0, 0, 0);
    __syncthreads();
  }

  // epilogue 2: relu, store upd, column sums
  float bup[4], s[4] = {0,0,0,0}, qq[4] = {0,0,0,0};
  #pragma unroll
  for (int j = 0; j < 4; j++) bup[j] = b_upd[wn + (j << 4) + cb];
  #pragma unroll
  for (int i = 0; i < 4; i++)
    #pragma unroll
    for (int r = 0; r < 4; r++) {
      const long gm = rowb + wm + (i << 4) + rb + r;            // flat row
      #pragma unroll
      for (int j = 0; j < 4; j++) {
        const int gn = wn + (j << 4) + cb;                      // o
        const float v = fmaxf(acc2[i][j][r] + bup[j], 0.f);
        upd[gm*HH + gn] = f2h(v);
        s[j] += v; qq[j] += v*v;
      }
    }
  #pragma unroll
  for (int j = 0; j < 4; j++) {
    const int gn = wn + (j << 4) + cb;
    atomicAdd(&colS[gn], s[j]);
    atomicAdd(&colQ[gn], qq[j]);
  }
  __syncthreads();
  if (tid < 128) {
    atomicAdd(&sums[tid],       colS[tid]);
    atomicAdd(&sums[128 + tid], colQ[tid]);
  }
}

// ---------------------------------------------------------------------------
__global__ __launch_bounds__(256) void final_k(const f16* __restrict__ upd,
    const float* __restrict__ node, const float* __restrict__ sums,
    const float* __restrict__ gamma, const float* __restrict__ beta,
    float* __restrict__ out)
{
  const long idx = (long)blockIdx.x*256 + threadIdx.x;   // float4 index
  const f16x4 u  = *(const f16x4*)&upd[idx << 2];
  const float4 nd = ((const float4*)node)[idx];
  const int ob = (idx & 31) << 2;
  const float inv = 1.0f/32768.0f;
  float4 res;
  #pragma unroll
  for (int c = 0; c < 4; c++) {
    const float m  = sums[ob + c]*inv;
    const float va = sums[128 + ob + c]*inv - m*m;
    const float sc = rsqrtf(va + EPS)*gamma[ob + c];
    ((float*)&res)[c] = ((float)u[c] - m)*sc + beta[ob + c]
                      + ((const float*)&nd)[c];
  }
  ((float4*)out)[idx] = res;
}

// ---------------------------------------------------------------------------
extern "C" void kernel_launch(void* const* d_in, const int* in_sizes, int n_in,
                              void* d_out, int out_size, void* d_ws, size_t ws_size,
                              hipStream_t stream) {
  const float* node  = (const float*)d_in[0];
  const float* E     = (const float*)d_in[1];
  const int*   adj   = (const int*)  d_in[2];
  const float* W_msg = (const float*)d_in[3];
  const float* b_msg = (const float*)d_in[4];
  const float* W_upd = (const float*)d_in[5];
  const float* b_upd = (const float*)d_in[6];
  const float* gamma = (const float*)d_in[7];
  const float* beta  = (const float*)d_in[8];
  float* out = (float*)d_out;

  char* p = (char*)d_ws;
  auto alloc = [&](size_t n) { void* r = (void*)p; p += (n + 255) & ~(size_t)255; return r; };
  f16*   h_part_T = (f16*)  alloc((size_t)BB*HH*NN*2);   // [b][o][i]  8 MB
  f16*   upd      = (f16*)  alloc((size_t)ROWS*HH*2);    // relu out   8 MB
  f16*   nodeh    = (f16*)  alloc((size_t)ROWS*HH*2);    // node f16   8 MB
  f16*   maskf    = (f16*)  alloc((size_t)NN*NN*2);      // mask[j][i] 2 MB
  f16*   maskT    = (f16*)  alloc((size_t)NN*NN*2);      // mask[i][j] 2 MB
  float* e_agg    = (float*)alloc((size_t)BB*NN*3*4);    // 384 KB
  f16*   Wh       = (f16*)  alloc((size_t)HH*HH*2);
  f16*   Wupd     = (f16*)  alloc((size_t)HH*256*2);
  float* We       = (float*)alloc((size_t)HH*3*4);
  float* sums     = (float*)alloc((size_t)256*4);

  prep0_k<<<135, 256, 0, stream>>>(W_msg, W_upd, node, adj,
                                   Wh, Wupd, We, nodeh, maskf, maskT,
                                   e_agg, sums);

  phaseB_k<<<2304, 256, 0, stream>>>(nodeh, E, maskT, Wh, b_msg, h_part_T, e_agg);

  gemm12_k<<<dim3(8, 1, BB), 256, 0, stream>>>(maskf, h_part_T, e_agg, We,
                                               nodeh, Wupd, b_upd, upd, sums);

  final_k<<<4096, 256, 0, stream>>>(upd, node, sums, gamma, beta, out);
}

// Round 4
// 624.834 us; speedup vs baseline: 1.1051x; 1.0094x over previous
//
#include <hip/hip_runtime.h>

typedef _Float16 f16;
typedef f16 f16x4 __attribute__((ext_vector_type(4)));
typedef f16 f16x8 __attribute__((ext_vector_type(8)));
typedef float f32x4 __attribute__((ext_vector_type(4)));

#define BB 32
#define NN 1024
#define HH 128
#define ROWS (BB*NN)          // 32768
#define EPS 1e-5f

__device__ __forceinline__ f16 f2h(float x) { return (f16)x; }

typedef __attribute__((address_space(1))) const void gv_t;
typedef __attribute__((address_space(3))) void lv_t;
__device__ __forceinline__ void gl_lds16(const void* g, void* l) {
  __builtin_amdgcn_global_load_lds((gv_t*)g, (lv_t*)l, 16, 0, 0);
}

// ---------------------------------------------------------------------------
// prep0 (135 blocks x 256) — all paths parallel, zeroing folded in.
//  blk 0..63   : node f32 -> f16 (nodeh)
//  blk 64..127 : adj 128x128 tile -> maskf (identity) + maskT (transpose)
//  blk 128     : Wh f16[128][128] from W_msg (stride 131)
//  blk 129     : Wupd f16[128][256]
//  blk 130     : We f32[128][3] + zero sums[256]
//  blk 131..134: zero e_agg
// ---------------------------------------------------------------------------
__global__ __launch_bounds__(256) void prep0_k(
    const float* __restrict__ W_msg, const float* __restrict__ W_upd,
    const float* __restrict__ node, const int* __restrict__ adj,
    f16* __restrict__ Wh, f16* __restrict__ Wupd, float* __restrict__ We,
    f16* __restrict__ nodeh, f16* __restrict__ maskf, f16* __restrict__ maskT,
    float* __restrict__ e_agg, float* __restrict__ sums)
{
  const int blk = blockIdx.x, t = threadIdx.x;
  if (blk < 64) {
    const long base = (long)blk*16384 + t;
    #pragma unroll
    for (int p = 0; p < 64; p++) {
      const long idx = base + (long)p*256;
      const float4 v = ((const float4*)node)[idx];
      f16x4 hv; hv[0] = f2h(v.x); hv[1] = f2h(v.y); hv[2] = f2h(v.z); hv[3] = f2h(v.w);
      *(f16x4*)&nodeh[idx << 2] = hv;
    }
  } else if (blk < 128) {
    __shared__ f16 ldsT[128][136];     // [i_local][j_local], padded
    const int tt = blk - 64, tj = tt >> 3, ti = tt & 7;
    #pragma unroll
    for (int p = 0; p < 16; p++) {
      const int q = p*256 + t;
      const int row = q >> 5, c4 = (q & 31) << 2;
      const int4 m = *(const int4*)&adj[(long)(tj*128 + row)*NN + ti*128 + c4];
      f16x4 hv;
      hv[0] = (m.x > 0) ? (f16)1.0f : (f16)0.0f;
      hv[1] = (m.y > 0) ? (f16)1.0f : (f16)0.0f;
      hv[2] = (m.z > 0) ? (f16)1.0f : (f16)0.0f;
      hv[3] = (m.w > 0) ? (f16)1.0f : (f16)0.0f;
      *(f16x4*)&maskf[(long)(tj*128 + row)*NN + ti*128 + c4] = hv;
      ldsT[c4 + 0][row] = hv[0];
      ldsT[c4 + 1][row] = hv[1];
      ldsT[c4 + 2][row] = hv[2];
      ldsT[c4 + 3][row] = hv[3];
    }
    __syncthreads();
    #pragma unroll
    for (int p = 0; p < 8; p++) {
      const int q = p*256 + t;
      const int rT = q >> 4, c8 = (q & 15) << 3;
      *(uint4*)&maskT[(long)(ti*128 + rT)*NN + tj*128 + c8] =
          *(const uint4*)&ldsT[rT][c8];
    }
  } else if (blk == 128) {
    for (int idx = t; idx < HH*HH; idx += 256) {
      const int o = idx >> 7, h = idx & 127;
      Wh[idx] = f2h(W_msg[o*131 + h]);
    }
  } else if (blk == 129) {
    for (int idx = t; idx < HH*256; idx += 256)
      Wupd[idx] = f2h(W_upd[idx]);
  } else if (blk == 130) {
    for (int idx = t; idx < HH*3; idx += 256)
      We[idx] = W_msg[(idx/3)*131 + 128 + (idx % 3)];
    if (t < 256) sums[t] = 0.f;
  } else {
    const int base = (blk - 131) * 24576 + t;
    #pragma unroll
    for (int r = 0; r < 96; r++) e_agg[base + r*256] = 0.f;
  }
}

// ---------------------------------------------------------------------------
// Phase B megakernel: 3328 blocks x 256.
//  blk [0,256): gemm0 — h_part_T[b][o][i] = sum_h Wh[o][h]*nodeh[b,i,h] + b_msg[o]
//  blk [256,3328): eagg (3072 blocks = 32 bb x 3 segs x 32 i-chunks):
//     register-direct, barrier-free, LDS-free masked reduction.
//     Thread owns float4 at p0 = seg*1024 + 4*tid of each row; row stride
//     3072 floats is a multiple of 3, so the (j,c) split of p0..p0+3 is
//     fixed across rows -> only masks j0 = p0/3 and j0+1 are ever needed.
// ---------------------------------------------------------------------------
__global__ __launch_bounds__(256) void phaseB_k(
    const f16* __restrict__ nodeh, const float* __restrict__ E,
    const f16* __restrict__ maskT, const f16* __restrict__ Wh,
    const float* __restrict__ b_msg,
    f16* __restrict__ h_part_T, float* __restrict__ e_agg)
{
  __shared__ __align__(16) char smem[16384];
  const int tid = threadIdx.x;

  if (blockIdx.x >= 256) {
    // ---- eagg path: no LDS, no barriers ----
    const int e   = blockIdx.x - 256;       // 0..3071
    const int bb  = e / 96;
    const int rem = e - bb*96;
    const int seg = rem >> 5;               // 0..2  (1024-float segment)
    const int ic  = rem & 31;               // 0..31 (32-row i-chunk)
    const int i0  = ic << 5;
    const int p0  = (seg << 10) + (tid << 2);   // element pos in row, 16B aligned
    const int j0  = p0 / 3;
    const int r   = p0 - j0*3;              // 0..2, fixed per thread
    const bool s1 = (r >= 2);               // k=1 uses m1 iff r==2
    const bool s2 = (r >= 1);               // k=2 uses m1 iff r>=1
    const float* Ep = E + (long)bb*3145728 + (long)i0*3072 + p0;
    const f16*   Mp = maskT + (long)i0*NN + j0;
    float a0 = 0.f, a1 = 0.f, a2 = 0.f, a3 = 0.f;
    for (int c8 = 0; c8 < 4; c8++) {
      float4 ev[8];
      float m0v[8], m1v[8];
      #pragma unroll
      for (int v = 0; v < 8; v++)
        ev[v] = *(const float4*)(Ep + (long)(c8*8 + v)*3072);
      #pragma unroll
      for (int v = 0; v < 8; v++) {
        const long moff = (long)(c8*8 + v)*NN;
        m0v[v] = (float)Mp[moff];
        m1v[v] = (float)Mp[moff + 1];
      }
      #pragma unroll
      for (int v = 0; v < 8; v++) {
        a0 = fmaf(m0v[v],              ev[v].x, a0);
        a1 = fmaf(s1 ? m1v[v] : m0v[v], ev[v].y, a1);
        a2 = fmaf(s2 ? m1v[v] : m0v[v], ev[v].z, a2);
        a3 = fmaf(m1v[v],              ev[v].w, a3);
      }
    }
    float* ebp = e_agg + (long)bb*3072 + p0;
    atomicAdd(ebp,     a0);
    atomicAdd(ebp + 1, a1);
    atomicAdd(ebp + 2, a2);
    atomicAdd(ebp + 3, a3);
    return;
  }

  // ---- gemm0 path: M=128 (o), N=128 tile (i), K=128, gl_lds staging ----
  f16* As = (f16*)smem;                     // 128x32
  f16* Bs = (f16*)(smem + 8192);            // 128x32
  const int g  = blockIdx.x;
  const int nt = g & 7, bb = g >> 3;
  const int nbase = nt << 7;
  const int lane = tid & 63, wave = tid >> 6;
  const int wm = (wave & 1) << 6, wn = (wave >> 1) << 6;

  f32x4 acc[2][4], acc2[2][4];
  #pragma unroll
  for (int i = 0; i < 2; i++)
    #pragma unroll
    for (int j = 0; j < 4; j++)
      #pragma unroll
      for (int r = 0; r < 4; r++) { acc[i][j][r] = 0.f; acc2[i][j][r] = 0.f; }

  for (int k0 = 0; k0 < HH; k0 += 32) {
    #pragma unroll
    for (int p = 0; p < 2; p++) {
      const int q = (p << 8) + tid;
      const int row = q >> 2, kp = (q & 3) << 3;
      gl_lds16(&Wh[(long)row*HH + k0 + kp], &As[q << 3]);
      gl_lds16(&nodeh[(long)((bb << 10) + nbase + row)*HH + k0 + kp], &Bs[q << 3]);
    }
    __syncthreads();
    f16x8 af[4], bf[4];
    #pragma unroll
    for (int i = 0; i < 4; i++) {
      af[i] = *(const f16x8*)&As[((wm + (i << 4) + (lane & 15)) << 5) + ((lane >> 4) << 3)];
      bf[i] = *(const f16x8*)&Bs[((wn + (i << 4) + (lane & 15)) << 5) + ((lane >> 4) << 3)];
    }
    #pragma unroll
    for (int i = 0; i < 2; i++)
      #pragma unroll
      for (int j = 0; j < 4; j++) {
        acc[i][j]  = __builtin_amdgcn_mfma_f32_16x16x32_f16(af[i],     bf[j], acc[i][j],  0, 0, 0);
        acc2[i][j] = __builtin_amdgcn_mfma_f32_16x16x32_f16(af[i + 2], bf[j], acc2[i][j], 0, 0, 0);
      }
    __syncthreads();
  }

  f16* out = h_part_T + (long)bb * (HH*NN);
  const int rb = (lane >> 4) << 2, cb = lane & 15;
  #pragma unroll
  for (int i = 0; i < 4; i++)
    #pragma unroll
    for (int r = 0; r < 4; r++) {
      const int gm = wm + (i << 4) + rb + r;                    // o
      const float bm = b_msg[gm];
      #pragma unroll
      for (int j = 0; j < 4; j++) {
        const int gn = nbase + wn + (j << 4) + cb;              // i
        const float v = ((i < 2) ? acc[i][j][r] : acc2[i - 2][j][r]) + bm;
        out[(long)gm*NN + gn] = f2h(v);
      }
    }
}

// ---------------------------------------------------------------------------
// gemm12 (fused): per block (mt, bb):
//  phase 1: msgs[j,o] = sum_i maskf[j,i]*hp[b][o][i] + e_agg·We  -> LDS (swizzled)
//  phase 2: updated = relu(concat(nodeh,msgs_lds) @ Wupd^T + b_upd) -> upd + sums
// ---------------------------------------------------------------------------
__global__ __launch_bounds__(256) void gemm12_k(
    const f16* __restrict__ maskf, const f16* __restrict__ hp,
    const float* __restrict__ e_agg, const float* __restrict__ We,
    const f16* __restrict__ nodeh, const f16* __restrict__ Wupd,
    const float* __restrict__ b_upd,
    f16* __restrict__ upd, float* __restrict__ sums)
{
  const int mt = blockIdx.x, bb = blockIdx.z;
  const int jb = mt << 7;                   // local j base
  const long rowb = (long)bb*NN + jb;       // flat row base
  __shared__ f16 As[128*32];
  __shared__ f16 Bs[128*32];
  __shared__ __align__(16) char msgs_lds[128*128*2];   // 32 KB, XOR-swizzled
  __shared__ float colS[128], colQ[128];
  const int tid = threadIdx.x, lane = tid & 63, wave = tid >> 6;
  const int wm = (wave & 1) << 6, wn = (wave >> 1) << 6;
  if (tid < 128) { colS[tid] = 0.f; colQ[tid] = 0.f; }
  const int rb = (lane >> 4) << 2, cb = lane & 15;

  // ---------------- phase 1: messages ----------------
  f32x4 acc[4][4];
  #pragma unroll
  for (int i = 0; i < 4; i++)
    #pragma unroll
    for (int j = 0; j < 4; j++)
      #pragma unroll
      for (int r = 0; r < 4; r++) acc[i][j][r] = 0.f;

  for (int k0 = 0; k0 < NN; k0 += 32) {
    #pragma unroll
    for (int p = 0; p < 2; p++) {
      const int q = (p << 8) + tid;
      const int row = q >> 2, kp = (q & 3) << 3;
      gl_lds16(&maskf[(long)(jb + row)*NN + k0 + kp], &As[q << 3]);
      gl_lds16(&hp[(long)bb*(HH*NN) + (long)row*NN + k0 + kp], &Bs[q << 3]);
    }
    __syncthreads();
    f16x8 af[4], bf[4];
    #pragma unroll
    for (int i = 0; i < 4; i++) {
      af[i] = *(const f16x8*)&As[((wm + (i << 4) + (lane & 15)) << 5) + ((lane >> 4) << 3)];
      bf[i] = *(const f16x8*)&Bs[((wn + (i << 4) + (lane & 15)) << 5) + ((lane >> 4) << 3)];
    }
    #pragma unroll
    for (int i = 0; i < 4; i++)
      #pragma unroll
      for (int j = 0; j < 4; j++)
        acc[i][j] = __builtin_amdgcn_mfma_f32_16x16x32_f16(af[i], bf[j], acc[i][j], 0, 0, 0);
    __syncthreads();
  }

  // epilogue 1: add e_agg·We, write msgs tile to swizzled LDS
  #pragma unroll
  for (int i = 0; i < 4; i++)
    #pragma unroll
    for (int r = 0; r < 4; r++) {
      const int lrow = wm + (i << 4) + rb + r;                  // local j
      const long eb = (rowb + lrow)*3;
      const float e0 = e_agg[eb], e1 = e_agg[eb+1], e2 = e_agg[eb+2];
      #pragma unroll
      for (int j = 0; j < 4; j++) {
        const int col = wn + (j << 4) + cb;                     // o
        const float v = acc[i][j][r]
                      + e0*We[col*3] + e1*We[col*3+1] + e2*We[col*3+2];
        const int byte = ((lrow << 8) + (col << 1)) ^ ((lrow & 7) << 4);
        *(f16*)(msgs_lds + byte) = f2h(v);
      }
    }
  __syncthreads();

  // ---------------- phase 2: update GEMM ----------------
  f32x4 acc2[4][4];
  #pragma unroll
  for (int i = 0; i < 4; i++)
    #pragma unroll
    for (int j = 0; j < 4; j++)
      #pragma unroll
      for (int r = 0; r < 4; r++) acc2[i][j][r] = 0.f;

  for (int k0 = 0; k0 < 256; k0 += 32) {
    const bool fromA = (k0 < HH);
    #pragma unroll
    for (int p = 0; p < 2; p++) {
      const int q = (p << 8) + tid;
      const int row = q >> 2, kp = (q & 3) << 3;
      if (fromA)
        gl_lds16(&nodeh[(rowb + row)*HH + k0 + kp], &As[q << 3]);
      gl_lds16(&Wupd[(long)row*256 + k0 + kp], &Bs[q << 3]);
    }
    __syncthreads();
    f16x8 af[4], bf[4];
    #pragma unroll
    for (int i = 0; i < 4; i++) {
      if (fromA) {
        af[i] = *(const f16x8*)&As[((wm + (i << 4) + (lane & 15)) << 5) + ((lane >> 4) << 3)];
      } else {
        const int lrow = wm + (i << 4) + (lane & 15);
        const int byte = ((lrow << 8) + (((k0 - HH) + ((lane >> 4) << 3)) << 1))
                         ^ ((lrow & 7) << 4);
        af[i] = *(const f16x8*)(msgs_lds + byte);
      }
      bf[i] = *(const f16x8*)&Bs[((wn + (i << 4) + (lane & 15)) << 5) + ((lane >> 4) << 3)];
    }
    #pragma unroll
    for (int i = 0; i < 4; i++)
      #pragma unroll
      for (int j = 0; j < 4; j++)
        acc2[i][j] = __builtin_amdgcn_mfma_f32_16x16x32_f16(af[i], bf[j], acc2[i][j], 0, 0, 0);
    __syncthreads();
  }

  // epilogue 2: relu, store upd, column sums
  float bup[4], s[4] = {0,0,0,0}, qq[4] = {0,0,0,0};
  #pragma unroll
  for (int j = 0; j < 4; j++) bup[j] = b_upd[wn + (j << 4) + cb];
  #pragma unroll
  for (int i = 0; i < 4; i++)
    #pragma unroll
    for (int r = 0; r < 4; r++) {
      const long gm = rowb + wm + (i << 4) + rb + r;            // flat row
      #pragma unroll
      for (int j = 0; j < 4; j++) {
        const int gn = wn + (j << 4) + cb;                      // o
        const float v = fmaxf(acc2[i][j][r] + bup[j], 0.f);
        upd[gm*HH + gn] = f2h(v);
        s[j] += v; qq[j] += v*v;
      }
    }
  #pragma unroll
  for (int j = 0; j < 4; j++) {
    const int gn = wn + (j << 4) + cb;
    atomicAdd(&colS[gn], s[j]);
    atomicAdd(&colQ[gn], qq[j]);
  }
  __syncthreads();
  if (tid < 128) {
    atomicAdd(&sums[tid],       colS[tid]);
    atomicAdd(&sums[128 + tid], colQ[tid]);
  }
}

// ---------------------------------------------------------------------------
__global__ __launch_bounds__(256) void final_k(const f16* __restrict__ upd,
    const float* __restrict__ node, const float* __restrict__ sums,
    const float* __restrict__ gamma, const float* __restrict__ beta,
    float* __restrict__ out)
{
  const long idx = (long)blockIdx.x*256 + threadIdx.x;   // float4 index
  const f16x4 u  = *(const f16x4*)&upd[idx << 2];
  const float4 nd = ((const float4*)node)[idx];
  const int ob = (idx & 31) << 2;
  const float inv = 1.0f/32768.0f;
  float4 res;
  #pragma unroll
  for (int c = 0; c < 4; c++) {
    const float m  = sums[ob + c]*inv;
    const float va = sums[128 + ob + c]*inv - m*m;
    const float sc = rsqrtf(va + EPS)*gamma[ob + c];
    ((float*)&res)[c] = ((float)u[c] - m)*sc + beta[ob + c]
                      + ((const float*)&nd)[c];
  }
  ((float4*)out)[idx] = res;
}

// ---------------------------------------------------------------------------
extern "C" void kernel_launch(void* const* d_in, const int* in_sizes, int n_in,
                              void* d_out, int out_size, void* d_ws, size_t ws_size,
                              hipStream_t stream) {
  const float* node  = (const float*)d_in[0];
  const float* E     = (const float*)d_in[1];
  const int*   adj   = (const int*)  d_in[2];
  const float* W_msg = (const float*)d_in[3];
  const float* b_msg = (const float*)d_in[4];
  const float* W_upd = (const float*)d_in[5];
  const float* b_upd = (const float*)d_in[6];
  const float* gamma = (const float*)d_in[7];
  const float* beta  = (const float*)d_in[8];
  float* out = (float*)d_out;

  char* p = (char*)d_ws;
  auto alloc = [&](size_t n) { void* r = (void*)p; p += (n + 255) & ~(size_t)255; return r; };
  f16*   h_part_T = (f16*)  alloc((size_t)BB*HH*NN*2);   // [b][o][i]  8 MB
  f16*   upd      = (f16*)  alloc((size_t)ROWS*HH*2);    // relu out   8 MB
  f16*   nodeh    = (f16*)  alloc((size_t)ROWS*HH*2);    // node f16   8 MB
  f16*   maskf    = (f16*)  alloc((size_t)NN*NN*2);      // mask[j][i] 2 MB
  f16*   maskT    = (f16*)  alloc((size_t)NN*NN*2);      // mask[i][j] 2 MB
  float* e_agg    = (float*)alloc((size_t)BB*NN*3*4);    // 384 KB
  f16*   Wh       = (f16*)  alloc((size_t)HH*HH*2);
  f16*   Wupd     = (f16*)  alloc((size_t)HH*256*2);
  float* We       = (float*)alloc((size_t)HH*3*4);
  float* sums     = (float*)alloc((size_t)256*4);

  prep0_k<<<135, 256, 0, stream>>>(W_msg, W_upd, node, adj,
                                   Wh, Wupd, We, nodeh, maskf, maskT,
                                   e_agg, sums);

  phaseB_k<<<3328, 256, 0, stream>>>(nodeh, E, maskT, Wh, b_msg, h_part_T, e_agg);

  gemm12_k<<<dim3(8, 1, BB), 256, 0, stream>>>(maskf, h_part_T, e_agg, We,
                                               nodeh, Wupd, b_upd, upd, sums);

  final_k<<<4096, 256, 0, stream>>>(upd, node, sums, gamma, beta, out);
}